// Round 17
// baseline (1358.795 us; speedup 1.0000x reference)
//
#include <hip/hip_runtime.h>
#include <hip/hip_bf16.h>

namespace {

constexpr int NN = 20000;   // nodes
constexpr int TT = 16;      // tokens per node
constexpr int DD = 256;     // hidden dim
constexpr int EE = 320000;  // edges
constexpr int BB = 64;      // graphs
constexpr int NLAY = 3;
constexpr int NGRUS = 4;
constexpr int D3 = 768;     // 3*D
constexpr int NRB = 157;    // row-blocks of 128
constexpr int NXCD = 8;

typedef __bf16 bf16x8 __attribute__((ext_vector_type(8)));
typedef float  f32x4  __attribute__((ext_vector_type(4)));

__device__ __forceinline__ float us2f(unsigned short u){
  union { unsigned int i; float f; } v; v.i = ((unsigned int)u) << 16; return v.f;
}
__device__ __forceinline__ unsigned short f2us(float f){
  union { float f; unsigned int i; } v; v.f = f;
  unsigned int r = v.i + 0x7fff + ((v.i >> 16) & 1);   // RNE
  return (unsigned short)(r >> 16);
}

// async global->LDS 16B per lane: LDS dest = wave-uniform base + lane*16 (linear)
__device__ __forceinline__ void gload16(const unsigned short* g, unsigned short* l){
  __builtin_amdgcn_global_load_lds(
      (const __attribute__((address_space(1))) unsigned int*)g,
      (__attribute__((address_space(3))) unsigned int*)l, 16, 0, 0);
}

// ---------------- init ----------------
__global__ void k_init(int* __restrict__ deg, int* __restrict__ cursor,
                       int* __restrict__ nmask, float* __restrict__ out){
  int i = blockIdx.x*256 + threadIdx.x;
  if (i < NN){ deg[i] = 0; cursor[i] = 0; nmask[i] = 1; }
  if (i < BB*DD) out[i] = 0.f;
}

// ---------------- embedding mean-pool: wave-per-node, float4 lanes ----------------
__global__ void k_embed(const int* __restrict__ xt, const float* __restrict__ emb,
                        unsigned short* __restrict__ h){
  int wid = threadIdx.x >> 6, lane = threadIdx.x & 63;
  int n = blockIdx.x*4 + wid;
  if (n >= NN) return;
  int tk = (lane < TT) ? xt[n*TT + lane] : 0;
  float a0 = 0.f, a1 = 0.f, a2 = 0.f, a3 = 0.f;
  int cnt = 0;
  #pragma unroll
  for (int t = 0; t < TT; ++t){
    int tok = __shfl(tk, t);           // wave-uniform -> no divergence
    if (tok != 0){
      ++cnt;
      float4 v = *reinterpret_cast<const float4*>(emb + (size_t)tok*DD + lane*4);
      a0 += v.x; a1 += v.y; a2 += v.z; a3 += v.w;
    }
  }
  float inv = 1.f / (float)(cnt > 0 ? cnt : 1);
  ushort4 o;
  o.x = f2us(a0*inv); o.y = f2us(a1*inv); o.z = f2us(a2*inv); o.w = f2us(a3*inv);
  *reinterpret_cast<ushort4*>(h + (size_t)n*DD + lane*4) = o;
}

// ---- WF[k][col] = sum_d W[k][d]*Wih[col][d]; store TRANSPOSED hi/lo bf16: WFT[col][k] ----
__global__ __launch_bounds__(256) void k_wf(const float* __restrict__ W,
                                            const float* __restrict__ Wih,
                                            unsigned short* __restrict__ WFThi,
                                            unsigned short* __restrict__ WFTlo){
  int lg = blockIdx.z; int l = lg / NGRUS;
  const float* A  = W   + (size_t)lg*DD*DD;   // [256][256]
  const float* Bm = Wih + (size_t)l*D3*DD;    // [768][256]
  unsigned short* oh = WFThi + (size_t)lg*D3*DD;  // [768][256]
  unsigned short* ol = WFTlo + (size_t)lg*D3*DD;
  int k0 = blockIdx.y*64, j0 = blockIdx.x*64;
  __shared__ float sA[16][68], sB[16][68];
  int tid = threadIdx.x, ty = tid/16, tx = tid%16;
  float acc[4][4] = {};
  int m = tid >> 2, dg = (tid & 3)*4;
  for (int d0 = 0; d0 < DD; d0 += 16){
    float4 ua = *reinterpret_cast<const float4*>(A  + (size_t)(k0+m)*DD + d0+dg);
    float4 ub = *reinterpret_cast<const float4*>(Bm + (size_t)(j0+m)*DD + d0+dg);
    __syncthreads();
    sA[dg+0][m]=ua.x; sA[dg+1][m]=ua.y; sA[dg+2][m]=ua.z; sA[dg+3][m]=ua.w;
    sB[dg+0][m]=ub.x; sB[dg+1][m]=ub.y; sB[dg+2][m]=ub.z; sB[dg+3][m]=ub.w;
    __syncthreads();
    #pragma unroll
    for (int dd = 0; dd < 16; ++dd){
      float a[4], b[4];
      #pragma unroll
      for (int i=0;i<4;++i) a[i] = sA[dd][ty*4+i];
      #pragma unroll
      for (int j=0;j<4;++j) b[j] = sB[dd][tx*4+j];
      #pragma unroll
      for (int i=0;i<4;++i)
        #pragma unroll
        for (int j=0;j<4;++j) acc[i][j] += a[i]*b[j];
    }
  }
  for (int i=0;i<4;++i){
    int k = k0 + ty*4 + i;
    for (int j=0;j<4;++j){
      int c = j0 + tx*4 + j;
      float v = acc[i][j];
      unsigned short hi = f2us(v);
      float rem = v - us2f(hi);
      oh[(size_t)c*DD + k] = hi;
      ol[(size_t)c*DD + k] = f2us(rem);
    }
  }
}

// ---- split Whh f32 [L][768][256] -> hi/lo bf16 same layout ----
__global__ void k_whh_split(const float* __restrict__ Whh, unsigned short* __restrict__ hi,
                            unsigned short* __restrict__ lo){
  size_t i = (size_t)blockIdx.x*256 + threadIdx.x;
  if (i >= (size_t)NLAY*D3*DD) return;
  float w = Whh[i];
  unsigned short h = f2us(w);
  hi[i] = h; lo[i] = f2us(w - us2f(h));
}

// ---------------- CSR build ----------------
__global__ void k_deg(const int* __restrict__ dst, int* __restrict__ deg){
  int e = blockIdx.x*256 + threadIdx.x; if (e < EE) atomicAdd(&deg[dst[e]], 1);
}
__global__ void k_scan(const int* __restrict__ deg, int* __restrict__ offs){
  __shared__ int part[1024];
  int t = threadIdx.x; const int CH = 20;
  int base = t*CH; int s = 0;
  for (int i = 0; i < CH; ++i){ int idx = base+i; if (idx < NN) s += deg[idx]; }
  part[t] = s; __syncthreads();
  for (int o = 1; o < 1024; o <<= 1){
    int v = part[t]; int add = (t >= o) ? part[t-o] : 0;
    __syncthreads(); part[t] = v + add; __syncthreads();
  }
  int run = (t > 0) ? part[t-1] : 0;
  for (int i = 0; i < CH; ++i){ int idx = base+i; if (idx < NN){ offs[idx] = run; run += deg[idx]; } }
  if (t == 1023) offs[NN] = run;
}
__global__ void k_fill_csr(const int* __restrict__ src, const int* __restrict__ dst,
                           const int* __restrict__ offs, int* __restrict__ cursor,
                           int* __restrict__ csr_src){
  int e = blockIdx.x*256 + threadIdx.x; if (e >= EE) return;
  int d = dst[e]; int pos = atomicAdd(&cursor[d], 1);
  csr_src[offs[d] + pos] = src[e];
}

// ---- batch is SORTED: starts via boundary scan (no atomics), counts = diff ----
__global__ void k_bounds(const int* __restrict__ batch, int* __restrict__ starts65){
  int n = blockIdx.x*256 + threadIdx.x;
  if (n >= NN) return;
  int b = batch[n];
  int p = (n == 0) ? -1 : batch[n-1];
  for (int bb = p+1; bb <= b; ++bb) starts65[bb] = n;
  if (n == NN-1){
    for (int bb = b+1; bb <= BB; ++bb) starts65[bb] = NN;
  }
}
__global__ void k_cnts(const int* __restrict__ starts65, int* __restrict__ counts){
  int b = threadIdx.x;
  if (b < BB) counts[b] = starts65[b+1] - starts65[b];
}

// ---------------- edge aggregation: wave-per-node, 64-index preload + shfl, 4-deep gathers ----------------
__global__ void k_agg(const unsigned short* __restrict__ h, const int* __restrict__ offs,
                      const int* __restrict__ csr_src, unsigned short* __restrict__ agg){
  int wid = threadIdx.x >> 6, lane = threadIdx.x & 63;
  int n = blockIdx.x*4 + wid;
  if (n >= NN) return;
  int s = offs[n], e = offs[n+1];
  float a0 = 0.f, a1 = 0.f, a2 = 0.f, a3 = 0.f;
  for (int base = s; base < e; base += 64){
    int cnt = min(64, e - base);
    int idx = (lane < cnt) ? csr_src[base + lane] : 0;   // one coalesced index load / 64 edges
    int i = 0;
    for (; i + 4 <= cnt; i += 4){
      int s0 = __shfl(idx, i+0), s1 = __shfl(idx, i+1);
      int s2 = __shfl(idx, i+2), s3 = __shfl(idx, i+3);
      ushort4 v0 = *reinterpret_cast<const ushort4*>(h + (size_t)s0*DD + lane*4);
      ushort4 v1 = *reinterpret_cast<const ushort4*>(h + (size_t)s1*DD + lane*4);
      ushort4 v2 = *reinterpret_cast<const ushort4*>(h + (size_t)s2*DD + lane*4);
      ushort4 v3 = *reinterpret_cast<const ushort4*>(h + (size_t)s3*DD + lane*4);
      a0 += us2f(v0.x); a1 += us2f(v0.y); a2 += us2f(v0.z); a3 += us2f(v0.w);
      a0 += us2f(v1.x); a1 += us2f(v1.y); a2 += us2f(v1.z); a3 += us2f(v1.w);
      a0 += us2f(v2.x); a1 += us2f(v2.y); a2 += us2f(v2.z); a3 += us2f(v2.w);
      a0 += us2f(v3.x); a1 += us2f(v3.y); a2 += us2f(v3.z); a3 += us2f(v3.w);
    }
    for (; i < cnt; ++i){
      int s0 = __shfl(idx, i);
      ushort4 v0 = *reinterpret_cast<const ushort4*>(h + (size_t)s0*DD + lane*4);
      a0 += us2f(v0.x); a1 += us2f(v0.y); a2 += us2f(v0.z); a3 += us2f(v0.w);
    }
  }
  ushort4 o;
  o.x = f2us(a0); o.y = f2us(a1); o.z = f2us(a2); o.w = f2us(a3);
  *reinterpret_cast<ushort4*>(agg + (size_t)n*DD + lane*4) = o;
}

// ---------------- fused MFMA GRU step (R14 exact): A reg-prefetch, B LDS dbuf ----------------
__global__ __launch_bounds__(256, 4) void k_gru(
    const unsigned short* __restrict__ Ag, const unsigned short* __restrict__ Ah,
    const unsigned short* __restrict__ WfH, const unsigned short* __restrict__ WfL,
    const unsigned short* __restrict__ WhH, const unsigned short* __restrict__ WhL,
    const float* __restrict__ bih, const float* __restrict__ bhh,
    const int* __restrict__ nmask, unsigned short* __restrict__ Hn, int do_relu){
  __shared__ unsigned short sB[2][96*64];    // rows 0-31 R, 32-63 Z, 64-95 N  12KB x2
  int t = threadIdx.x;
  int wv = t >> 6, lane = t & 63;
  int lr = lane & 15, kg = lane >> 4;

  int w = blockIdx.x;
  int q = (w & 7)*NRB + (w >> 3);
  int r0 = (q >> 3) * 128;
  int g0 = q & 7;                            // col-group [0,8)

  int sw   = ((lane & 7) ^ (lane >> 3)) * 8; // pre-swizzled source chunk offset (elems)
  int rloc = lane >> 3;                      // row within 8-row segment

  auto stageB = [&](int buf, int p){
    int a = p >> 1;
    const unsigned short* m = (p & 1) ? ((a & 4) ? WhL : WfL)
                                      : ((a & 4) ? WhH : WfH);
    int kin0 = (a & 3) * 64;
    #pragma unroll
    for (int i = 0; i < 3; ++i){
      int brow = (wv + i*4)*8;               // 0,8,...,88
      int gate = brow >> 5;
      int srcrow = gate*256 + g0*32 + (brow & 31) + rloc;
      gload16(m + (size_t)srcrow*DD + kin0 + sw, &sB[buf][brow*64]);
    }
  };

  f32x4 aR[2][2], aZ[2][2], aNi[2][2], aNh[2][2];   // [row-frag][col-half]
  #pragma unroll
  for (int rf = 0; rf < 2; ++rf)
    #pragma unroll
    for (int h2 = 0; h2 < 2; ++h2){
      aR[rf][h2] = (f32x4){0.f,0.f,0.f,0.f};  aZ[rf][h2] = (f32x4){0.f,0.f,0.f,0.f};
      aNi[rf][h2] = (f32x4){0.f,0.f,0.f,0.f}; aNh[rf][h2] = (f32x4){0.f,0.f,0.f,0.f};
    }

  size_t arow0 = (size_t)(r0 + wv*32 + lr) * DD;
  size_t arow1 = (size_t)(r0 + wv*32 + 16 + lr) * DD;

  bf16x8 aF0[2][2], aF1[2][2];               // [parity][kk2]
  #pragma unroll
  for (int kk2 = 0; kk2 < 2; ++kk2){         // prologue: A frags for a=0 (Ag, kin 0)
    aF0[0][kk2] = *reinterpret_cast<const bf16x8*>(Ag + arow0 + kk2*32 + kg*8);
    aF1[0][kk2] = *reinterpret_cast<const bf16x8*>(Ag + arow1 + kk2*32 + kg*8);
  }
  stageB(0, 0);

  #pragma unroll
  for (int a = 0; a < 8; ++a){
    int par = a & 1;
    int half = (a >> 2) & 1;                  // 0: Ag-block (Ni), 1: Ah-block (Nh)
    #pragma unroll
    for (int ph = 0; ph < 2; ++ph){           // 0: hi weights, 1: lo weights
      int p = a*2 + ph;
      int bbuf = p & 1;
      __syncthreads();                        // vmcnt drained -> sB[bbuf] staged
      if (p < 15) stageB(bbuf ^ 1, p + 1);    // async prefetch next phase's B
      if (ph == 0 && a < 7){                  // prefetch next A-block's frags (regs)
        const unsigned short* An = ((a+1) & 4) ? Ah : Ag;
        int kinn = ((a+1) & 3) * 64;
        #pragma unroll
        for (int kk2 = 0; kk2 < 2; ++kk2){
          aF0[par ^ 1][kk2] = *reinterpret_cast<const bf16x8*>(An + arow0 + kinn + kk2*32 + kg*8);
          aF1[par ^ 1][kk2] = *reinterpret_cast<const bf16x8*>(An + arow1 + kinn + kk2*32 + kg*8);
        }
      }
      __builtin_amdgcn_s_setprio(1);
      #pragma unroll
      for (int kk2 = 0; kk2 < 2; ++kk2){
        int cs = ((kk2*4 + kg) ^ (lr & 7)) * 8; // swizzled read slot
        bf16x8 a0 = aF0[par][kk2];
        bf16x8 a1 = aF1[par][kk2];
        #pragma unroll
        for (int h2 = 0; h2 < 2; ++h2){
          bf16x8 bR = *reinterpret_cast<const bf16x8*>(&sB[bbuf][(      h2*16 + lr)*64 + cs]);
          bf16x8 bZ = *reinterpret_cast<const bf16x8*>(&sB[bbuf][(32  + h2*16 + lr)*64 + cs]);
          bf16x8 bN = *reinterpret_cast<const bf16x8*>(&sB[bbuf][(64  + h2*16 + lr)*64 + cs]);
          aR[0][h2] = __builtin_amdgcn_mfma_f32_16x16x32_bf16(a0, bR, aR[0][h2], 0, 0, 0);
          aR[1][h2] = __builtin_amdgcn_mfma_f32_16x16x32_bf16(a1, bR, aR[1][h2], 0, 0, 0);
          aZ[0][h2] = __builtin_amdgcn_mfma_f32_16x16x32_bf16(a0, bZ, aZ[0][h2], 0, 0, 0);
          aZ[1][h2] = __builtin_amdgcn_mfma_f32_16x16x32_bf16(a1, bZ, aZ[1][h2], 0, 0, 0);
          if (half){
            aNh[0][h2] = __builtin_amdgcn_mfma_f32_16x16x32_bf16(a0, bN, aNh[0][h2], 0, 0, 0);
            aNh[1][h2] = __builtin_amdgcn_mfma_f32_16x16x32_bf16(a1, bN, aNh[1][h2], 0, 0, 0);
          } else {
            aNi[0][h2] = __builtin_amdgcn_mfma_f32_16x16x32_bf16(a0, bN, aNi[0][h2], 0, 0, 0);
            aNi[1][h2] = __builtin_amdgcn_mfma_f32_16x16x32_bf16(a1, bN, aNi[1][h2], 0, 0, 0);
          }
        }
      }
      __builtin_amdgcn_s_setprio(0);
    }
  }

  // epilogue: per-lane GRU math. C layout: col=lane&15, row=kg*4+j (16x16 tiles)
  #pragma unroll
  for (int h2 = 0; h2 < 2; ++h2){
    int col = g0*32 + h2*16 + lr;
    float bRv = bih[col]       + bhh[col];
    float bZv = bih[256 + col] + bhh[256 + col];
    float bN1 = bih[512 + col];
    float bN2 = bhh[512 + col];
    #pragma unroll
    for (int rf = 0; rf < 2; ++rf){
      #pragma unroll
      for (int j = 0; j < 4; ++j){
        int row = r0 + wv*32 + rf*16 + kg*4 + j;
        if (row < NN){
          float r = 1.f/(1.f + expf(-(aR[rf][h2][j] + bRv)));
          float z = 1.f/(1.f + expf(-(aZ[rf][h2][j] + bZv)));
          float nv = tanhf(aNi[rf][h2][j] + bN1 + r*(aNh[rf][h2][j] + bN2));
          float ho = us2f(Ah[(size_t)row*DD + col]);
          float o = (1.f - z)*nv + z*ho;
          if (do_relu) o = fmaxf(o, 0.f);
          if (!nmask[row]) o = 0.f;
          Hn[(size_t)row*DD + col] = f2us(o);
        }
      }
    }
  }
}

// ---------------- fused per-graph pool: score -> topk -> scale -> attention ----------------
// Race-fixed: keep flags go to kp[] (separate array); sc[] is only mutated AFTER the
// rank loop completes (barrier). Phase D uses kp[] (block-local) for validity.
__global__ __launch_bounds__(256) void k_pool(
    unsigned short* __restrict__ h, const float* __restrict__ p,
    const float* __restrict__ gW, const float* __restrict__ gb,
    const int* __restrict__ starts, const int* __restrict__ counts,
    int* __restrict__ nmask, float* __restrict__ outacc){
  int b = blockIdx.x; int st = starts[b]; int cnt = min(counts[b], 1024);
  __shared__ float sc[1024]; __shared__ int kp[1024];
  __shared__ float red[256]; __shared__ int ired[256];
  __shared__ float s_pnorm;
  int t = threadIdx.x, wid = t >> 6, lane = t & 63;

  // ---- phase A: raw dots per node (one node per wave) ----
  float4 pv = *reinterpret_cast<const float4*>(p + lane*4);
  {
    float pp = pv.x*pv.x + pv.y*pv.y + pv.z*pv.z + pv.w*pv.w;
    for (int o = 32; o; o >>= 1) pp += __shfl_down(pp, o);
    if (t == 0) s_pnorm = sqrtf(pp);
  }
  for (int i = wid; i < cnt; i += 4){
    int node = st + i;
    ushort4 hu = *reinterpret_cast<const ushort4*>(h + (size_t)node*DD + lane*4);
    float dot = us2f(hu.x)*pv.x + us2f(hu.y)*pv.y + us2f(hu.z)*pv.z + us2f(hu.w)*pv.w;
    for (int o = 32; o; o >>= 1) dot += __shfl_down(dot, o);
    if (lane == 0) sc[i] = dot;
  }
  __syncthreads();
  float pnorm = s_pnorm;

  // ---- phase B1: finalize scores + count valid ----
  int myvalid = 0;
  for (int i = t; i < cnt; i += 256){
    int node = st + i; int v = nmask[node];
    float s = tanhf(sc[i] / pnorm);
    sc[i] = v ? s : -1e30f;
    myvalid += v;
  }
  ired[t] = myvalid; __syncthreads();
  for (int o = 128; o; o >>= 1){ if (t < o) ired[t] += ired[t+o]; __syncthreads(); }
  int nv = ired[0];
  int k = (4*nv + 4)/5;   // == ceil(0.8*nv)
  __syncthreads();

  // ---- phase B2: rank select -> kp[] only (sc NOT mutated here) ----
  for (int i = t; i < cnt; i += 256){
    float si = sc[i]; int node = st + i; int keep = 0;
    if (si > -1e29f){
      int rank = 0;
      for (int j = 0; j < cnt; ++j){
        float sj = sc[j];
        rank += (sj > si) || (sj == si && j < i);
      }
      keep = (rank < k);
    }
    kp[i] = keep;
    nmask[node] = keep;
  }
  __syncthreads();

  // ---- phase B3: apply keep to scale factors (post-barrier, race-free) ----
  for (int i = t; i < cnt; i += 256)
    if (!kp[i]) sc[i] = 0.f;
  __syncthreads();

  // ---- phase C: h *= score (thread t owns dim t) ----
  for (int i = 0; i < cnt; ++i){
    size_t idx = (size_t)(st + i)*DD + t;
    float s = sc[i];
    h[idx] = (s == 0.f) ? (unsigned short)0 : f2us(us2f(h[idx])*s);
  }
  __syncthreads();

  // ---- phase D: global attention with scaled h ----
  float4 wv4 = *reinterpret_cast<const float4*>(gW + lane*4);
  float gbv = gb[0];
  for (int i = wid; i < cnt; i += 4){
    int node = st + i;
    ushort4 hu = *reinterpret_cast<const ushort4*>(h + (size_t)node*DD + lane*4);
    float dot = us2f(hu.x)*wv4.x + us2f(hu.y)*wv4.y + us2f(hu.z)*wv4.z + us2f(hu.w)*wv4.w;
    for (int o = 32; o; o >>= 1) dot += __shfl_down(dot, o);
    if (lane == 0) sc[i] = kp[i] ? dot + gbv : -1e30f;
  }
  __syncthreads();
  float mx = -1e30f;
  for (int i = t; i < cnt; i += 256) mx = fmaxf(mx, sc[i]);
  red[t] = mx; __syncthreads();
  for (int o = 128; o; o >>= 1){ if (t < o) red[t] = fmaxf(red[t], red[t+o]); __syncthreads(); }
  mx = red[0]; __syncthreads();
  float se = 0.f;
  for (int i = t; i < cnt; i += 256){
    float e = (sc[i] > -1e29f) ? expf(sc[i] - mx) : 0.f;
    sc[i] = e; se += e;
  }
  red[t] = se; __syncthreads();
  for (int o = 128; o; o >>= 1){ if (t < o) red[t] += red[t+o]; __syncthreads(); }
  float denom = fmaxf(red[0], 1e-12f);
  __syncthreads();
  float a0=0.f,a1=0.f,a2=0.f,a3=0.f;
  int i = 0;
  for (; i + 4 <= cnt; i += 4){
    a0 += sc[i+0]*us2f(h[(size_t)(st+i+0)*DD + t]);
    a1 += sc[i+1]*us2f(h[(size_t)(st+i+1)*DD + t]);
    a2 += sc[i+2]*us2f(h[(size_t)(st+i+2)*DD + t]);
    a3 += sc[i+3]*us2f(h[(size_t)(st+i+3)*DD + t]);
  }
  for (; i < cnt; ++i) a0 += sc[i]*us2f(h[(size_t)(st+i)*DD + t]);
  outacc[(size_t)b*DD + t] += (a0+a1+a2+a3)/denom;
}

} // namespace

extern "C" void kernel_launch(void* const* d_in, const int* in_sizes, int n_in,
                              void* d_out, int out_size, void* d_ws, size_t ws_size,
                              hipStream_t stream){
  const int*   x_tokens = (const int*)d_in[0];
  const int*   e_src    = (const int*)d_in[1];
  const int*   e_dst    = e_src + EE;
  const int*   batch    = (const int*)d_in[2];
  const float* embed    = (const float*)d_in[3];
  const float* ggcW     = (const float*)d_in[4];
  const float* gWih     = (const float*)d_in[5];
  const float* gWhh     = (const float*)d_in[6];
  const float* gbih     = (const float*)d_in[7];
  const float* gbhh     = (const float*)d_in[8];
  const float* topkp    = (const float*)d_in[9];
  const float* gateW    = (const float*)d_in[10];
  const float* gateb    = (const float*)d_in[11];
  (void)in_sizes; (void)n_in; (void)out_size;
  float* out = (float*)d_out;

  char* ws = (char*)d_ws;
  size_t off = 0;
  auto carve = [&](size_t bytes)->char*{
    char* p = ws + off;
    off += (bytes + 255) & ~(size_t)255;
    return p;
  };
  unsigned short* h0    = (unsigned short*)carve((size_t)NN*DD*2);
  unsigned short* h1    = (unsigned short*)carve((size_t)NN*DD*2);
  unsigned short* agg   = (unsigned short*)carve((size_t)NN*DD*2);
  unsigned short* WFThi = (unsigned short*)carve((size_t)NLAY*NGRUS*D3*DD*2);
  unsigned short* WFTlo = (unsigned short*)carve((size_t)NLAY*NGRUS*D3*DD*2);
  unsigned short* WhhHi = (unsigned short*)carve((size_t)NLAY*D3*DD*2);
  unsigned short* WhhLo = (unsigned short*)carve((size_t)NLAY*D3*DD*2);
  int* nmask     = (int*)carve((size_t)NN*4);
  int* deg       = (int*)carve((size_t)NN*4);
  int* cursor    = (int*)carve((size_t)NN*4);
  int* offs      = (int*)carve((size_t)(NN+1)*4);
  int* csr_src   = (int*)carve((size_t)EE*4);
  int* counts    = (int*)carve((size_t)BB*4);
  int* starts    = (int*)carve((size_t)(BB+1)*4);
  if (off > ws_size) return;  // ~45 MB total

  k_init<<<(NN+255)/256, 256, 0, stream>>>(deg, cursor, nmask, out);
  k_embed<<<(NN+3)/4, 256, 0, stream>>>(x_tokens, embed, h0);
  k_wf<<<dim3(D3/64, DD/64, NLAY*NGRUS), 256, 0, stream>>>(ggcW, gWih, WFThi, WFTlo);
  k_whh_split<<<(NLAY*D3*DD + 255)/256, 256, 0, stream>>>(gWhh, WhhHi, WhhLo);
  k_deg<<<(EE+255)/256, 256, 0, stream>>>(e_dst, deg);
  k_scan<<<1, 1024, 0, stream>>>(deg, offs);
  k_fill_csr<<<(EE+255)/256, 256, 0, stream>>>(e_src, e_dst, offs, cursor, csr_src);
  k_bounds<<<(NN+255)/256, 256, 0, stream>>>(batch, starts);
  k_cnts<<<1, 64, 0, stream>>>(starts, counts);

  unsigned short* hc = h0; unsigned short* hn = h1;
  for (int l = 0; l < NLAY; ++l){
    const unsigned short* WhHl = WhhHi + (size_t)l*D3*DD;
    const unsigned short* WhLl = WhhLo + (size_t)l*D3*DD;
    const float* bihl = gbih + (size_t)l*D3;
    const float* bhhl = gbhh + (size_t)l*D3;
    for (int g = 0; g < NGRUS; ++g){
      const unsigned short* WfHl = WFThi + (size_t)(l*NGRUS+g)*D3*DD;
      const unsigned short* WfLl = WFTlo + (size_t)(l*NGRUS+g)*D3*DD;
      k_agg<<<(NN+3)/4, 256, 0, stream>>>(hc, offs, csr_src, agg);
      k_gru<<<NRB*NXCD, 256, 0, stream>>>(agg, hc, WfHl, WfLl, WhHl, WhLl,
                                          bihl, bhhl, nmask, hn,
                                          (g == NGRUS-1) ? 1 : 0);
      unsigned short* tmp = hc; hc = hn; hn = tmp;
    }
    k_pool<<<BB, 256, 0, stream>>>(hc, topkp + (size_t)l*DD, gateW, gateb,
                                   starts, counts, nmask, out);
  }
}

// Round 18
// 1233.152 us; speedup vs baseline: 1.1019x; 1.1019x over previous
//
#include <hip/hip_runtime.h>
#include <hip/hip_bf16.h>

namespace {

constexpr int NN = 20000;   // nodes
constexpr int TT = 16;      // tokens per node
constexpr int DD = 256;     // hidden dim
constexpr int EE = 320000;  // edges
constexpr int BB = 64;      // graphs
constexpr int NLAY = 3;
constexpr int NGRUS = 4;
constexpr int D3 = 768;     // 3*D
constexpr int NRB = 157;    // row-blocks of 128
constexpr int NXCD = 8;

typedef __bf16 bf16x8 __attribute__((ext_vector_type(8)));
typedef float  f32x4  __attribute__((ext_vector_type(4)));

__device__ __forceinline__ float us2f(unsigned short u){
  union { unsigned int i; float f; } v; v.i = ((unsigned int)u) << 16; return v.f;
}
__device__ __forceinline__ unsigned short f2us(float f){
  union { float f; unsigned int i; } v; v.f = f;
  unsigned int r = v.i + 0x7fff + ((v.i >> 16) & 1);   // RNE
  return (unsigned short)(r >> 16);
}

// async global->LDS 16B per lane: LDS dest = wave-uniform base + lane*16 (linear)
__device__ __forceinline__ void gload16(const unsigned short* g, unsigned short* l){
  __builtin_amdgcn_global_load_lds(
      (const __attribute__((address_space(1))) unsigned int*)g,
      (__attribute__((address_space(3))) unsigned int*)l, 16, 0, 0);
}

// ---------------- init ----------------
__global__ void k_init(int* __restrict__ deg, int* __restrict__ cursor,
                       int* __restrict__ nmask, float* __restrict__ out){
  int i = blockIdx.x*256 + threadIdx.x;
  if (i < NN){ deg[i] = 0; cursor[i] = 0; nmask[i] = 1; }
  if (i < BB*DD) out[i] = 0.f;
}

// ---------------- embedding mean-pool: wave-per-node, float4 lanes ----------------
__global__ void k_embed(const int* __restrict__ xt, const float* __restrict__ emb,
                        unsigned short* __restrict__ h){
  int wid = threadIdx.x >> 6, lane = threadIdx.x & 63;
  int n = blockIdx.x*4 + wid;
  if (n >= NN) return;
  int tk = (lane < TT) ? xt[n*TT + lane] : 0;
  float a0 = 0.f, a1 = 0.f, a2 = 0.f, a3 = 0.f;
  int cnt = 0;
  #pragma unroll
  for (int t = 0; t < TT; ++t){
    int tok = __shfl(tk, t);           // wave-uniform -> no divergence
    if (tok != 0){
      ++cnt;
      float4 v = *reinterpret_cast<const float4*>(emb + (size_t)tok*DD + lane*4);
      a0 += v.x; a1 += v.y; a2 += v.z; a3 += v.w;
    }
  }
  float inv = 1.f / (float)(cnt > 0 ? cnt : 1);
  ushort4 o;
  o.x = f2us(a0*inv); o.y = f2us(a1*inv); o.z = f2us(a2*inv); o.w = f2us(a3*inv);
  *reinterpret_cast<ushort4*>(h + (size_t)n*DD + lane*4) = o;
}

// ---- WF[k][col] = sum_d W[k][d]*Wih[col][d]; store TRANSPOSED hi/lo bf16: WFT[col][k] ----
__global__ __launch_bounds__(256) void k_wf(const float* __restrict__ W,
                                            const float* __restrict__ Wih,
                                            unsigned short* __restrict__ WFThi,
                                            unsigned short* __restrict__ WFTlo){
  int lg = blockIdx.z; int l = lg / NGRUS;
  const float* A  = W   + (size_t)lg*DD*DD;   // [256][256]
  const float* Bm = Wih + (size_t)l*D3*DD;    // [768][256]
  unsigned short* oh = WFThi + (size_t)lg*D3*DD;  // [768][256]
  unsigned short* ol = WFTlo + (size_t)lg*D3*DD;
  int k0 = blockIdx.y*64, j0 = blockIdx.x*64;
  __shared__ float sA[16][68], sB[16][68];
  int tid = threadIdx.x, ty = tid/16, tx = tid%16;
  float acc[4][4] = {};
  int m = tid >> 2, dg = (tid & 3)*4;
  for (int d0 = 0; d0 < DD; d0 += 16){
    float4 ua = *reinterpret_cast<const float4*>(A  + (size_t)(k0+m)*DD + d0+dg);
    float4 ub = *reinterpret_cast<const float4*>(Bm + (size_t)(j0+m)*DD + d0+dg);
    __syncthreads();
    sA[dg+0][m]=ua.x; sA[dg+1][m]=ua.y; sA[dg+2][m]=ua.z; sA[dg+3][m]=ua.w;
    sB[dg+0][m]=ub.x; sB[dg+1][m]=ub.y; sB[dg+2][m]=ub.z; sB[dg+3][m]=ub.w;
    __syncthreads();
    #pragma unroll
    for (int dd = 0; dd < 16; ++dd){
      float a[4], b[4];
      #pragma unroll
      for (int i=0;i<4;++i) a[i] = sA[dd][ty*4+i];
      #pragma unroll
      for (int j=0;j<4;++j) b[j] = sB[dd][tx*4+j];
      #pragma unroll
      for (int i=0;i<4;++i)
        #pragma unroll
        for (int j=0;j<4;++j) acc[i][j] += a[i]*b[j];
    }
  }
  for (int i=0;i<4;++i){
    int k = k0 + ty*4 + i;
    for (int j=0;j<4;++j){
      int c = j0 + tx*4 + j;
      float v = acc[i][j];
      unsigned short hi = f2us(v);
      float rem = v - us2f(hi);
      oh[(size_t)c*DD + k] = hi;
      ol[(size_t)c*DD + k] = f2us(rem);
    }
  }
}

// ---- split Whh f32 [L][768][256] -> hi/lo bf16 same layout ----
__global__ void k_whh_split(const float* __restrict__ Whh, unsigned short* __restrict__ hi,
                            unsigned short* __restrict__ lo){
  size_t i = (size_t)blockIdx.x*256 + threadIdx.x;
  if (i >= (size_t)NLAY*D3*DD) return;
  float w = Whh[i];
  unsigned short h = f2us(w);
  hi[i] = h; lo[i] = f2us(w - us2f(h));
}

// ---------------- CSR build ----------------
__global__ void k_deg(const int* __restrict__ dst, int* __restrict__ deg){
  int e = blockIdx.x*256 + threadIdx.x; if (e < EE) atomicAdd(&deg[dst[e]], 1);
}
__global__ void k_scan(const int* __restrict__ deg, int* __restrict__ offs){
  __shared__ int part[1024];
  int t = threadIdx.x; const int CH = 20;
  int base = t*CH; int s = 0;
  for (int i = 0; i < CH; ++i){ int idx = base+i; if (idx < NN) s += deg[idx]; }
  part[t] = s; __syncthreads();
  for (int o = 1; o < 1024; o <<= 1){
    int v = part[t]; int add = (t >= o) ? part[t-o] : 0;
    __syncthreads(); part[t] = v + add; __syncthreads();
  }
  int run = (t > 0) ? part[t-1] : 0;
  for (int i = 0; i < CH; ++i){ int idx = base+i; if (idx < NN){ offs[idx] = run; run += deg[idx]; } }
  if (t == 1023) offs[NN] = run;
}
__global__ void k_fill_csr(const int* __restrict__ src, const int* __restrict__ dst,
                           const int* __restrict__ offs, int* __restrict__ cursor,
                           int* __restrict__ csr_src){
  int e = blockIdx.x*256 + threadIdx.x; if (e >= EE) return;
  int d = dst[e]; int pos = atomicAdd(&cursor[d], 1);
  csr_src[offs[d] + pos] = src[e];
}

// ---- batch is SORTED: starts via boundary scan (no atomics), counts = diff ----
__global__ void k_bounds(const int* __restrict__ batch, int* __restrict__ starts65){
  int n = blockIdx.x*256 + threadIdx.x;
  if (n >= NN) return;
  int b = batch[n];
  int p = (n == 0) ? -1 : batch[n-1];
  for (int bb = p+1; bb <= b; ++bb) starts65[bb] = n;
  if (n == NN-1){
    for (int bb = b+1; bb <= BB; ++bb) starts65[bb] = NN;
  }
}
__global__ void k_cnts(const int* __restrict__ starts65, int* __restrict__ counts){
  int b = threadIdx.x;
  if (b < BB) counts[b] = starts65[b+1] - starts65[b];
}

// ---------------- edge aggregation: wave-per-node, 64-index preload + shfl, 4-deep gathers ----------------
__global__ void k_agg(const unsigned short* __restrict__ h, const int* __restrict__ offs,
                      const int* __restrict__ csr_src, unsigned short* __restrict__ agg){
  int wid = threadIdx.x >> 6, lane = threadIdx.x & 63;
  int n = blockIdx.x*4 + wid;
  if (n >= NN) return;
  int s = offs[n], e = offs[n+1];
  float a0 = 0.f, a1 = 0.f, a2 = 0.f, a3 = 0.f;
  for (int base = s; base < e; base += 64){
    int cnt = min(64, e - base);
    int idx = (lane < cnt) ? csr_src[base + lane] : 0;   // one coalesced index load / 64 edges
    int i = 0;
    for (; i + 4 <= cnt; i += 4){
      int s0 = __shfl(idx, i+0), s1 = __shfl(idx, i+1);
      int s2 = __shfl(idx, i+2), s3 = __shfl(idx, i+3);
      ushort4 v0 = *reinterpret_cast<const ushort4*>(h + (size_t)s0*DD + lane*4);
      ushort4 v1 = *reinterpret_cast<const ushort4*>(h + (size_t)s1*DD + lane*4);
      ushort4 v2 = *reinterpret_cast<const ushort4*>(h + (size_t)s2*DD + lane*4);
      ushort4 v3 = *reinterpret_cast<const ushort4*>(h + (size_t)s3*DD + lane*4);
      a0 += us2f(v0.x); a1 += us2f(v0.y); a2 += us2f(v0.z); a3 += us2f(v0.w);
      a0 += us2f(v1.x); a1 += us2f(v1.y); a2 += us2f(v1.z); a3 += us2f(v1.w);
      a0 += us2f(v2.x); a1 += us2f(v2.y); a2 += us2f(v2.z); a3 += us2f(v2.w);
      a0 += us2f(v3.x); a1 += us2f(v3.y); a2 += us2f(v3.z); a3 += us2f(v3.w);
    }
    for (; i < cnt; ++i){
      int s0 = __shfl(idx, i);
      ushort4 v0 = *reinterpret_cast<const ushort4*>(h + (size_t)s0*DD + lane*4);
      a0 += us2f(v0.x); a1 += us2f(v0.y); a2 += us2f(v0.z); a3 += us2f(v0.w);
    }
  }
  ushort4 o;
  o.x = f2us(a0); o.y = f2us(a1); o.z = f2us(a2); o.w = f2us(a3);
  *reinterpret_cast<ushort4*>(agg + (size_t)n*DD + lane*4) = o;
}

// ---------------- fused MFMA GRU step: A reg-prefetched 1 phase ahead, B LDS-staged ----------------
__global__ __launch_bounds__(256, 4) void k_gru(
    const unsigned short* __restrict__ Ag, const unsigned short* __restrict__ Ah,
    const unsigned short* __restrict__ WfH, const unsigned short* __restrict__ WfL,
    const unsigned short* __restrict__ WhH, const unsigned short* __restrict__ WhL,
    const float* __restrict__ bih, const float* __restrict__ bhh,
    const int* __restrict__ nmask, unsigned short* __restrict__ Hn, int do_relu){
  __shared__ unsigned short sB[2][96*64];    // rows 0-31 R, 32-63 Z, 64-95 N  12KB x2
  int t = threadIdx.x;
  int wv = t >> 6, lane = t & 63;
  int lr = lane & 15, kg = lane >> 4;

  int w = blockIdx.x;
  int q = (w & 7)*NRB + (w >> 3);
  int r0 = (q >> 3) * 128;
  int g0 = q & 7;                            // col-group [0,8)

  int sw   = ((lane & 7) ^ (lane >> 3)) * 8; // pre-swizzled source chunk offset (elems)
  int rloc = lane >> 3;                      // row within 8-row segment

  auto stageB = [&](int buf, int p){
    int a = p >> 1;
    const unsigned short* m = (p & 1) ? ((a & 4) ? WhL : WfL)
                                      : ((a & 4) ? WhH : WfH);
    int kin0 = (a & 3) * 64;
    #pragma unroll
    for (int i = 0; i < 3; ++i){
      int brow = (wv + i*4)*8;               // 0,8,...,88
      int gate = brow >> 5;
      int srcrow = gate*256 + g0*32 + (brow & 31) + rloc;
      gload16(m + (size_t)srcrow*DD + kin0 + sw, &sB[buf][brow*64]);
    }
  };

  f32x4 aR[2][2], aZ[2][2], aNi[2][2], aNh[2][2];   // [row-frag][col-half]
  #pragma unroll
  for (int rf = 0; rf < 2; ++rf)
    #pragma unroll
    for (int h2 = 0; h2 < 2; ++h2){
      aR[rf][h2] = (f32x4){0.f,0.f,0.f,0.f};  aZ[rf][h2] = (f32x4){0.f,0.f,0.f,0.f};
      aNi[rf][h2] = (f32x4){0.f,0.f,0.f,0.f}; aNh[rf][h2] = (f32x4){0.f,0.f,0.f,0.f};
    }

  size_t arow0 = (size_t)(r0 + wv*32 + lr) * DD;
  size_t arow1 = (size_t)(r0 + wv*32 + 16 + lr) * DD;

  bf16x8 aF0[2][2], aF1[2][2];               // [parity][kk2]
  #pragma unroll
  for (int kk2 = 0; kk2 < 2; ++kk2){         // prologue: A frags for a=0 (Ag, kin 0)
    aF0[0][kk2] = *reinterpret_cast<const bf16x8*>(Ag + arow0 + kk2*32 + kg*8);
    aF1[0][kk2] = *reinterpret_cast<const bf16x8*>(Ag + arow1 + kk2*32 + kg*8);
  }
  stageB(0, 0);

  #pragma unroll
  for (int a = 0; a < 8; ++a){
    int par = a & 1;
    int half = (a >> 2) & 1;                  // 0: Ag-block (Ni), 1: Ah-block (Nh)
    #pragma unroll
    for (int ph = 0; ph < 2; ++ph){           // 0: hi weights, 1: lo weights
      int p = a*2 + ph;
      int bbuf = p & 1;
      __syncthreads();                        // vmcnt drained -> sB[bbuf] staged
      if (p < 15) stageB(bbuf ^ 1, p + 1);    // async prefetch next phase's B
      if (ph == 0 && a < 7){                  // prefetch next A-block's frags (regs)
        const unsigned short* An = ((a+1) & 4) ? Ah : Ag;
        int kinn = ((a+1) & 3) * 64;
        #pragma unroll
        for (int kk2 = 0; kk2 < 2; ++kk2){
          aF0[par ^ 1][kk2] = *reinterpret_cast<const bf16x8*>(An + arow0 + kinn + kk2*32 + kg*8);
          aF1[par ^ 1][kk2] = *reinterpret_cast<const bf16x8*>(An + arow1 + kinn + kk2*32 + kg*8);
        }
      }
      __builtin_amdgcn_s_setprio(1);
      #pragma unroll
      for (int kk2 = 0; kk2 < 2; ++kk2){
        int cs = ((kk2*4 + kg) ^ (lr & 7)) * 8; // swizzled read slot
        bf16x8 a0 = aF0[par][kk2];
        bf16x8 a1 = aF1[par][kk2];
        #pragma unroll
        for (int h2 = 0; h2 < 2; ++h2){
          bf16x8 bR = *reinterpret_cast<const bf16x8*>(&sB[bbuf][(      h2*16 + lr)*64 + cs]);
          bf16x8 bZ = *reinterpret_cast<const bf16x8*>(&sB[bbuf][(32  + h2*16 + lr)*64 + cs]);
          bf16x8 bN = *reinterpret_cast<const bf16x8*>(&sB[bbuf][(64  + h2*16 + lr)*64 + cs]);
          aR[0][h2] = __builtin_amdgcn_mfma_f32_16x16x32_bf16(a0, bR, aR[0][h2], 0, 0, 0);
          aR[1][h2] = __builtin_amdgcn_mfma_f32_16x16x32_bf16(a1, bR, aR[1][h2], 0, 0, 0);
          aZ[0][h2] = __builtin_amdgcn_mfma_f32_16x16x32_bf16(a0, bZ, aZ[0][h2], 0, 0, 0);
          aZ[1][h2] = __builtin_amdgcn_mfma_f32_16x16x32_bf16(a1, bZ, aZ[1][h2], 0, 0, 0);
          if (half){
            aNh[0][h2] = __builtin_amdgcn_mfma_f32_16x16x32_bf16(a0, bN, aNh[0][h2], 0, 0, 0);
            aNh[1][h2] = __builtin_amdgcn_mfma_f32_16x16x32_bf16(a1, bN, aNh[1][h2], 0, 0, 0);
          } else {
            aNi[0][h2] = __builtin_amdgcn_mfma_f32_16x16x32_bf16(a0, bN, aNi[0][h2], 0, 0, 0);
            aNi[1][h2] = __builtin_amdgcn_mfma_f32_16x16x32_bf16(a1, bN, aNi[1][h2], 0, 0, 0);
          }
        }
      }
      __builtin_amdgcn_s_setprio(0);
    }
  }

  // epilogue: per-lane GRU math. C layout: col=lane&15, row=kg*4+j (16x16 tiles)
  #pragma unroll
  for (int h2 = 0; h2 < 2; ++h2){
    int col = g0*32 + h2*16 + lr;
    float bRv = bih[col]       + bhh[col];
    float bZv = bih[256 + col] + bhh[256 + col];
    float bN1 = bih[512 + col];
    float bN2 = bhh[512 + col];
    #pragma unroll
    for (int rf = 0; rf < 2; ++rf){
      #pragma unroll
      for (int j = 0; j < 4; ++j){
        int row = r0 + wv*32 + rf*16 + kg*4 + j;
        if (row < NN){
          float r = 1.f/(1.f + expf(-(aR[rf][h2][j] + bRv)));
          float z = 1.f/(1.f + expf(-(aZ[rf][h2][j] + bZv)));
          float nv = tanhf(aNi[rf][h2][j] + bN1 + r*(aNh[rf][h2][j] + bN2));
          float ho = us2f(Ah[(size_t)row*DD + col]);
          float o = (1.f - z)*nv + z*ho;
          if (do_relu) o = fmaxf(o, 0.f);
          if (!nmask[row]) o = 0.f;
          Hn[(size_t)row*DD + col] = f2us(o);
        }
      }
    }
  }
}

// ---------------- topk score ----------------
__global__ void k_score(const unsigned short* __restrict__ h, const float* __restrict__ p,
                        float* __restrict__ score){
  int wid = threadIdx.x >> 6, lane = threadIdx.x & 63;
  int n = blockIdx.x*4 + wid; if (n >= NN) return;
  ushort4 hu = *reinterpret_cast<const ushort4*>(h + (size_t)n*DD + lane*4);
  float4 pv = *reinterpret_cast<const float4*>(p + lane*4);
  float dot = us2f(hu.x)*pv.x + us2f(hu.y)*pv.y + us2f(hu.z)*pv.z + us2f(hu.w)*pv.w;
  float pp = pv.x*pv.x + pv.y*pv.y + pv.z*pv.z + pv.w*pv.w;
  for (int o = 32; o; o >>= 1){ dot += __shfl_down(dot, o); pp += __shfl_down(pp, o); }
  if (lane == 0) score[n] = tanhf(dot / sqrtf(pp));
}

// ---------------- per-graph topk (score desc, tie -> lower index) ----------------
__global__ void k_topk(const float* __restrict__ score, const int* __restrict__ starts,
                       const int* __restrict__ counts, int* __restrict__ nmask){
  int b = blockIdx.x; int st = starts[b]; int cnt = min(counts[b], 1024);
  __shared__ float sc[1024]; __shared__ int ired[256];
  int t = threadIdx.x;
  int myvalid = 0;
  for (int i = t; i < cnt; i += 256){
    int node = st + i; int v = nmask[node];
    sc[i] = v ? score[node] : -1e30f;
    myvalid += v;
  }
  ired[t] = myvalid; __syncthreads();
  for (int o = 128; o; o >>= 1){ if (t < o) ired[t] += ired[t+o]; __syncthreads(); }
  int nv = ired[0];
  int k = (4*nv + 4)/5;   // == ceil(0.8*nv)
  __syncthreads();
  for (int i = t; i < cnt; i += 256){
    float si = sc[i]; int node = st + i; int keep = 0;
    if (si > -1e29f){
      int rank = 0;
      for (int j = 0; j < cnt; ++j){
        float sj = sc[j];
        rank += (sj > si) || (sj == si && j < i);
      }
      keep = (rank < k);
    }
    nmask[node] = keep;
  }
}

__global__ void k_scale(unsigned short* __restrict__ h, const float* __restrict__ score,
                        const int* __restrict__ nmask){
  int idx = blockIdx.x*256 + threadIdx.x;
  int n = idx >> 8;
  unsigned short v = nmask[n] ? f2us(us2f(h[idx])*score[n]) : (unsigned short)0;
  h[idx] = v;
}

// ---------------- global attention per graph, accumulates into d_out (f32) ----------------
__global__ void k_att(const unsigned short* __restrict__ h, const float* __restrict__ gW,
                      const float* __restrict__ gb, const int* __restrict__ starts,
                      const int* __restrict__ counts, const int* __restrict__ nmask,
                      float* __restrict__ outacc){
  int b = blockIdx.x; int st = starts[b]; int cnt = min(counts[b], 1024);
  __shared__ float lg[1024]; __shared__ float red[256];
  int t = threadIdx.x, wid = t >> 6, lane = t & 63;
  float gbv = gb[0];
  for (int i = wid; i < cnt; i += 4){
    int node = st + i;
    ushort4 hu = *reinterpret_cast<const ushort4*>(h + (size_t)node*DD + lane*4);
    float4 wv = *reinterpret_cast<const float4*>(gW + lane*4);
    float dot = us2f(hu.x)*wv.x + us2f(hu.y)*wv.y + us2f(hu.z)*wv.z + us2f(hu.w)*wv.w;
    for (int o = 32; o; o >>= 1) dot += __shfl_down(dot, o);
    if (lane == 0) lg[i] = nmask[node] ? dot + gbv : -1e30f;
  }
  __syncthreads();
  float mx = -1e30f;
  for (int i = t; i < cnt; i += 256) mx = fmaxf(mx, lg[i]);
  red[t] = mx; __syncthreads();
  for (int o = 128; o; o >>= 1){ if (t < o) red[t] = fmaxf(red[t], red[t+o]); __syncthreads(); }
  mx = red[0]; __syncthreads();
  float se = 0.f;
  for (int i = t; i < cnt; i += 256){
    float e = (lg[i] > -1e29f) ? expf(lg[i] - mx) : 0.f;
    lg[i] = e; se += e;
  }
  red[t] = se; __syncthreads();
  for (int o = 128; o; o >>= 1){ if (t < o) red[t] += red[t+o]; __syncthreads(); }
  float denom = fmaxf(red[0], 1e-12f);
  __syncthreads();
  float a0=0.f,a1=0.f,a2=0.f,a3=0.f;
  int i = 0;
  for (; i + 4 <= cnt; i += 4){
    a0 += lg[i+0]*us2f(h[(size_t)(st+i+0)*DD + t]);
    a1 += lg[i+1]*us2f(h[(size_t)(st+i+1)*DD + t]);
    a2 += lg[i+2]*us2f(h[(size_t)(st+i+2)*DD + t]);
    a3 += lg[i+3]*us2f(h[(size_t)(st+i+3)*DD + t]);
  }
  for (; i < cnt; ++i) a0 += lg[i]*us2f(h[(size_t)(st+i)*DD + t]);
  outacc[(size_t)b*DD + t] += (a0+a1+a2+a3)/denom;
}

} // namespace

extern "C" void kernel_launch(void* const* d_in, const int* in_sizes, int n_in,
                              void* d_out, int out_size, void* d_ws, size_t ws_size,
                              hipStream_t stream){
  const int*   x_tokens = (const int*)d_in[0];
  const int*   e_src    = (const int*)d_in[1];
  const int*   e_dst    = e_src + EE;
  const int*   batch    = (const int*)d_in[2];
  const float* embed    = (const float*)d_in[3];
  const float* ggcW     = (const float*)d_in[4];
  const float* gWih     = (const float*)d_in[5];
  const float* gWhh     = (const float*)d_in[6];
  const float* gbih     = (const float*)d_in[7];
  const float* gbhh     = (const float*)d_in[8];
  const float* topkp    = (const float*)d_in[9];
  const float* gateW    = (const float*)d_in[10];
  const float* gateb    = (const float*)d_in[11];
  (void)in_sizes; (void)n_in; (void)out_size;
  float* out = (float*)d_out;

  char* ws = (char*)d_ws;
  size_t off = 0;
  auto carve = [&](size_t bytes)->char*{
    char* p = ws + off;
    off += (bytes + 255) & ~(size_t)255;
    return p;
  };
  unsigned short* h0    = (unsigned short*)carve((size_t)NN*DD*2);
  unsigned short* h1    = (unsigned short*)carve((size_t)NN*DD*2);
  unsigned short* agg   = (unsigned short*)carve((size_t)NN*DD*2);
  unsigned short* WFThi = (unsigned short*)carve((size_t)NLAY*NGRUS*D3*DD*2);
  unsigned short* WFTlo = (unsigned short*)carve((size_t)NLAY*NGRUS*D3*DD*2);
  unsigned short* WhhHi = (unsigned short*)carve((size_t)NLAY*D3*DD*2);
  unsigned short* WhhLo = (unsigned short*)carve((size_t)NLAY*D3*DD*2);
  float* score   = (float*)carve((size_t)NN*4);
  int* nmask     = (int*)carve((size_t)NN*4);
  int* deg       = (int*)carve((size_t)NN*4);
  int* cursor    = (int*)carve((size_t)NN*4);
  int* offs      = (int*)carve((size_t)(NN+1)*4);
  int* csr_src   = (int*)carve((size_t)EE*4);
  int* counts    = (int*)carve((size_t)BB*4);
  int* starts    = (int*)carve((size_t)(BB+1)*4);
  if (off > ws_size) return;  // ~45 MB total

  k_init<<<(NN+255)/256, 256, 0, stream>>>(deg, cursor, nmask, out);
  k_embed<<<(NN+3)/4, 256, 0, stream>>>(x_tokens, embed, h0);
  k_wf<<<dim3(D3/64, DD/64, NLAY*NGRUS), 256, 0, stream>>>(ggcW, gWih, WFThi, WFTlo);
  k_whh_split<<<(NLAY*D3*DD + 255)/256, 256, 0, stream>>>(gWhh, WhhHi, WhhLo);
  k_deg<<<(EE+255)/256, 256, 0, stream>>>(e_dst, deg);
  k_scan<<<1, 1024, 0, stream>>>(deg, offs);
  k_fill_csr<<<(EE+255)/256, 256, 0, stream>>>(e_src, e_dst, offs, cursor, csr_src);
  k_bounds<<<(NN+255)/256, 256, 0, stream>>>(batch, starts);
  k_cnts<<<1, 64, 0, stream>>>(starts, counts);

  unsigned short* hc = h0; unsigned short* hn = h1;
  for (int l = 0; l < NLAY; ++l){
    const unsigned short* WhHl = WhhHi + (size_t)l*D3*DD;
    const unsigned short* WhLl = WhhLo + (size_t)l*D3*DD;
    const float* bihl = gbih + (size_t)l*D3;
    const float* bhhl = gbhh + (size_t)l*D3;
    for (int g = 0; g < NGRUS; ++g){
      const unsigned short* WfHl = WFThi + (size_t)(l*NGRUS+g)*D3*DD;
      const unsigned short* WfLl = WFTlo + (size_t)(l*NGRUS+g)*D3*DD;
      k_agg<<<(NN+3)/4, 256, 0, stream>>>(hc, offs, csr_src, agg);
      k_gru<<<NRB*NXCD, 256, 0, stream>>>(agg, hc, WfHl, WfLl, WhHl, WhLl,
                                          bihl, bhhl, nmask, hn,
                                          (g == NGRUS-1) ? 1 : 0);
      unsigned short* tmp = hc; hc = hn; hn = tmp;
    }
    k_score<<<NN/4, 256, 0, stream>>>(hc, topkp + (size_t)l*DD, score);
    k_topk<<<BB, 256, 0, stream>>>(score, starts, counts, nmask);
    k_scale<<<NN, 256, 0, stream>>>(hc, score, nmask);
    k_att<<<BB, 256, 0, stream>>>(hc, gateW, gateb, starts, counts, nmask, out);
  }
}